// Round 1
// baseline (2283.048 us; speedup 1.0000x reference)
//
#include <hip/hip_runtime.h>

// EdgeSoftmax: scores = exp(logits - segmax(logits, dst)); normalizer = segsum(scores, dst)
// logits: [E, H] f32, dst: [E] i32 in [0,N), outputs: scores [E,H] f32 ++ normalizer [N,H] f32
//
// Pass 0: init max workspace (N*H f32 in d_ws) to -inf, normalizer (in d_out) to 0.
// Pass 1: per-edge atomic float-max scatter into max workspace.
// Pass 2: per-edge gather max, exp, write scores, atomic-add scatter into normalizer.

__device__ __forceinline__ void atomicMaxFloat(float* addr, float value) {
    // Exact float max via monotone bit-pattern trick (no NaNs in inputs).
    if (value >= 0.0f)
        atomicMax((int*)addr, __float_as_int(value));
    else
        atomicMin((unsigned int*)addr, __float_as_uint(value));
}

__global__ void es_init_kernel(unsigned int* __restrict__ maxws,
                               float* __restrict__ norm, int nh) {
    int i = blockIdx.x * blockDim.x + threadIdx.x;
    if (i < nh) {
        maxws[i] = 0xFF800000u;  // -inf bit pattern
        norm[i] = 0.0f;
    }
}

// ---- fast path: H == 8 (one thread per edge, float4 x2 loads) ----

__global__ void es_max_h8_kernel(const float* __restrict__ logits,
                                 const int* __restrict__ dst,
                                 float* __restrict__ maxws, int E) {
    int e = blockIdx.x * blockDim.x + threadIdx.x;
    if (e >= E) return;
    int d = dst[e];
    const float4* lp = (const float4*)(logits + (size_t)e * 8);
    float4 a = lp[0];
    float4 b = lp[1];
    float* base = maxws + (size_t)d * 8;
    atomicMaxFloat(base + 0, a.x);
    atomicMaxFloat(base + 1, a.y);
    atomicMaxFloat(base + 2, a.z);
    atomicMaxFloat(base + 3, a.w);
    atomicMaxFloat(base + 4, b.x);
    atomicMaxFloat(base + 5, b.y);
    atomicMaxFloat(base + 6, b.z);
    atomicMaxFloat(base + 7, b.w);
}

__global__ void es_score_h8_kernel(const float* __restrict__ logits,
                                   const int* __restrict__ dst,
                                   const float* __restrict__ maxws,
                                   float* __restrict__ scores,
                                   float* __restrict__ norm, int E) {
    int e = blockIdx.x * blockDim.x + threadIdx.x;
    if (e >= E) return;
    int d = dst[e];
    const float4* lp = (const float4*)(logits + (size_t)e * 8);
    float4 a = lp[0];
    float4 b = lp[1];
    const float4* mp = (const float4*)(maxws + (size_t)d * 8);
    float4 m0 = mp[0];
    float4 m1 = mp[1];
    float4 s0, s1;
    s0.x = __expf(a.x - m0.x);
    s0.y = __expf(a.y - m0.y);
    s0.z = __expf(a.z - m0.z);
    s0.w = __expf(a.w - m0.w);
    s1.x = __expf(b.x - m1.x);
    s1.y = __expf(b.y - m1.y);
    s1.z = __expf(b.z - m1.z);
    s1.w = __expf(b.w - m1.w);
    float4* sp = (float4*)(scores + (size_t)e * 8);
    sp[0] = s0;
    sp[1] = s1;
    float* nb = norm + (size_t)d * 8;
    atomicAdd(nb + 0, s0.x);
    atomicAdd(nb + 1, s0.y);
    atomicAdd(nb + 2, s0.z);
    atomicAdd(nb + 3, s0.w);
    atomicAdd(nb + 4, s1.x);
    atomicAdd(nb + 5, s1.y);
    atomicAdd(nb + 6, s1.z);
    atomicAdd(nb + 7, s1.w);
}

// ---- generic fallback: any H (one thread per (edge, head) element) ----

__global__ void es_max_gen_kernel(const float* __restrict__ logits,
                                  const int* __restrict__ dst,
                                  float* __restrict__ maxws,
                                  int total, int H) {
    int i = blockIdx.x * blockDim.x + threadIdx.x;
    if (i >= total) return;
    int e = i / H;
    int h = i - e * H;
    atomicMaxFloat(maxws + (size_t)dst[e] * H + h, logits[i]);
}

__global__ void es_score_gen_kernel(const float* __restrict__ logits,
                                    const int* __restrict__ dst,
                                    const float* __restrict__ maxws,
                                    float* __restrict__ scores,
                                    float* __restrict__ norm,
                                    int total, int H) {
    int i = blockIdx.x * blockDim.x + threadIdx.x;
    if (i >= total) return;
    int e = i / H;
    int h = i - e * H;
    size_t idx = (size_t)dst[e] * H + h;
    float s = __expf(logits[i] - maxws[idx]);
    scores[i] = s;
    atomicAdd(norm + idx, s);
}

extern "C" void kernel_launch(void* const* d_in, const int* in_sizes, int n_in,
                              void* d_out, int out_size, void* d_ws, size_t ws_size,
                              hipStream_t stream) {
    const float* logits = (const float*)d_in[0];
    const int* dst = (const int*)d_in[1];
    const int EH = in_sizes[0];      // E*H
    const int E = in_sizes[1];       // edges
    const int H = EH / E;            // heads (8)
    const int NH = out_size - EH;    // N*H (normalizer element count)

    float* scores = (float*)d_out;
    float* norm = (float*)d_out + (size_t)EH;
    float* maxws = (float*)d_ws;     // N*H floats

    const int threads = 256;

    // Pass 0: init
    {
        int blocks = (NH + threads - 1) / threads;
        hipLaunchKernelGGL(es_init_kernel, dim3(blocks), dim3(threads), 0, stream,
                           (unsigned int*)maxws, norm, NH);
    }

    if (H == 8) {
        int blocks = (E + threads - 1) / threads;
        hipLaunchKernelGGL(es_max_h8_kernel, dim3(blocks), dim3(threads), 0, stream,
                           logits, dst, maxws, E);
        hipLaunchKernelGGL(es_score_h8_kernel, dim3(blocks), dim3(threads), 0, stream,
                           logits, dst, maxws, scores, norm, E);
    } else {
        int blocks = (EH + threads - 1) / threads;
        hipLaunchKernelGGL(es_max_gen_kernel, dim3(blocks), dim3(threads), 0, stream,
                           logits, dst, maxws, EH, H);
        hipLaunchKernelGGL(es_score_gen_kernel, dim3(blocks), dim3(threads), 0, stream,
                           logits, dst, maxws, scores, norm, EH, H);
    }
}